// Round 1
// baseline (8210.084 us; speedup 1.0000x reference)
//
#include <hip/hip_runtime.h>

typedef unsigned int u32;
typedef unsigned short u16;

#define NIN 7
#define NH 64
#define NHC 32
#define NHQ 16
#define NOUT 3
#define NB 256
#define NS 2048

// ---- LDS layout ----
// weights (ushort units)
#define WS_OFF 0          // 256 rows x 88  : [0..6]=x-w, [7]=bias, [8..71]=hs-w, pad
#define WC_OFF 22528      // 384 rows x 120 : att 0..127, vel 128..255, pos 256..383
                          //   [0..6]=x-w(0 for pos), [7]=bias, [8..39]=hh-w, [40..103]=hs-w, [104..106]=d-w, pad
#define WM1_OFF 68608     // 48 rows x 40   : [0..31]=w, [32]=bias, pad   (att 0..15, vel 16..31, pos 32..47)
#define WM2_OFF 70528     // 9 rows x 24    : [0..15]=w, [16]=bias, pad   (att 0..2, vel 3..5, pos 6..8)
#define WTOT 70744
#define FOFF_BYTES 141488  // WTOT*2, 16B aligned
// f32 region (float units from F)
#define XBo 0      // 16 (two x buffers of 8; slot[7]=1.0 each)
#define HAo 16     // 32
#define HVo 48     // 32
#define HPo 80     // 32
#define ZSo 112    // 256
#define ZCo 368    // 384
#define ZPH 752    // 128
#define FTOT 880
#define SMEM_BYTES (FOFF_BYTES + FTOT*4)   // 145008

__device__ inline float blo(u32 u){ return __uint_as_float(u << 16); }
__device__ inline float bhi(u32 u){ return __uint_as_float(u & 0xffff0000u); }
__device__ inline float b16f(u16 u){ return __uint_as_float(((u32)u) << 16); }

__device__ inline u16 f2bf(float f){            // round-to-nearest-even
  u32 u = __float_as_uint(f);
  u32 r = u + 0x7fffu + ((u >> 16) & 1u);
  return (u16)(r >> 16);
}

__device__ inline float sigf(float x){ return 1.f/(1.f + __expf(-x)); }
__device__ inline float tanhf_(float x){ return 1.f - 2.f/(1.f + __expf(2.f*x)); }

template<int J>
__device__ inline float rlf(float v){
  return __uint_as_float((u32)__builtin_amdgcn_readlane((int)__float_as_uint(v), J));
}

__device__ inline uint4 ld4(const u16* p){ return *(const uint4*)p; }

// acc += sum_{i<8} w[i] * lane(J0+i) of src
template<int J0>
__device__ inline void d8(float& a, uint4 w, float src){
  a = fmaf(blo(w.x), rlf<J0+0>(src), a);
  a = fmaf(bhi(w.x), rlf<J0+1>(src), a);
  a = fmaf(blo(w.y), rlf<J0+2>(src), a);
  a = fmaf(bhi(w.y), rlf<J0+3>(src), a);
  a = fmaf(blo(w.z), rlf<J0+4>(src), a);
  a = fmaf(bhi(w.z), rlf<J0+5>(src), a);
  a = fmaf(blo(w.w), rlf<J0+6>(src), a);
  a = fmaf(bhi(w.w), rlf<J0+7>(src), a);
}

template<int J0>
__device__ inline void d8_2(float& a, float& b, uint4 wa, uint4 wb, float src){
  float s;
  s = rlf<J0+0>(src); a = fmaf(blo(wa.x), s, a); b = fmaf(blo(wb.x), s, b);
  s = rlf<J0+1>(src); a = fmaf(bhi(wa.x), s, a); b = fmaf(bhi(wb.x), s, b);
  s = rlf<J0+2>(src); a = fmaf(blo(wa.y), s, a); b = fmaf(blo(wb.y), s, b);
  s = rlf<J0+3>(src); a = fmaf(bhi(wa.y), s, a); b = fmaf(bhi(wb.y), s, b);
  s = rlf<J0+4>(src); a = fmaf(blo(wa.z), s, a); b = fmaf(blo(wb.z), s, b);
  s = rlf<J0+5>(src); a = fmaf(bhi(wa.z), s, a); b = fmaf(bhi(wb.z), s, b);
  s = rlf<J0+6>(src); a = fmaf(blo(wa.w), s, a); b = fmaf(blo(wb.w), s, b);
  s = rlf<J0+7>(src); a = fmaf(bhi(wa.w), s, a); b = fmaf(bhi(wb.w), s, b);
}

// 32-elem dot: elems [0..31] at p, act lanes J 0..31
__device__ inline void dotc4(float& a, const u16* p8, float src){
  const uint4* p = (const uint4*)p8;
  d8<0>(a, p[0], src); d8<8>(a, p[1], src); d8<16>(a, p[2], src); d8<24>(a, p[3], src);
}
// 64-elem dot
__device__ inline void dotc8(float& a, const u16* p8, float src){
  const uint4* p = (const uint4*)p8;
  d8<0>(a, p[0], src);  d8<8>(a, p[1], src);  d8<16>(a, p[2], src); d8<24>(a, p[3], src);
  d8<32>(a, p[4], src); d8<40>(a, p[5], src); d8<48>(a, p[6], src); d8<56>(a, p[7], src);
}
// hi half: elems [32..63] of a 64-block starting at p8, act lanes 32..63
__device__ inline void dotc4hi(float& a, const u16* p8, float src){
  const uint4* p = (const uint4*)p8;
  d8<32>(a, p[4], src); d8<40>(a, p[5], src); d8<48>(a, p[6], src); d8<56>(a, p[7], src);
}
// 64-elem dot, two rows sharing broadcasts
__device__ inline void dotc8_2(float& a, float& b, const u16* ra, const u16* rb, float src){
  const uint4* pa = (const uint4*)ra; const uint4* pb = (const uint4*)rb;
  d8_2<0>(a,b,pa[0],pb[0],src);  d8_2<8>(a,b,pa[1],pb[1],src);
  d8_2<16>(a,b,pa[2],pb[2],src); d8_2<24>(a,b,pa[3],pb[3],src);
  d8_2<32>(a,b,pa[4],pb[4],src); d8_2<40>(a,b,pa[5],pb[5],src);
  d8_2<48>(a,b,pa[6],pb[6],src); d8_2<56>(a,b,pa[7],pb[7],src);
}

__device__ inline float mlp1f(const u16* row, float src){   // relu(bias + dot32)
  float a = b16f(row[32]);
  dotc4(a, row, src);
  return fmaxf(a, 0.f);
}
__device__ inline float mlp2f(const u16* row, float src){   // bias + dot16
  float a = b16f(row[16]);
  const uint4* p = (const uint4*)row;
  d8<0>(a, p[0], src); d8<8>(a, p[1], src);
  return a;
}

__global__ __launch_bounds__(256) void mtinn_kernel(
    const float* __restrict__ x,
    const float* wihs, const float* whhs, const float* bihs, const float* bhhs,
    const float* wiha, const float* whha, const float* biha, const float* bhha,
    const float* wihv, const float* whhv, const float* bihv, const float* bhhv,
    const float* wihp, const float* whhp, const float* bihp, const float* bhhp,
    const float* wa1, const float* ba1, const float* wa2, const float* ba2,
    const float* wv1, const float* bv1, const float* wv2, const float* bv2,
    const float* wp1, const float* bp1, const float* wp2, const float* bp2,
    float* __restrict__ out)
{
  extern __shared__ char smem[];
  u16* WL  = (u16*)smem;
  float* F = (float*)(smem + FOFF_BYTES);
  const int tid  = threadIdx.x;
  const int b    = blockIdx.x;
  const int wave = tid >> 6, lane = tid & 63;
  const float* xb = x + (size_t)b * NS * NIN;

  // ================= init: weights -> LDS (bf16 RNE) =================
  {   // shared row r = tid
    int r = tid;
    u16* row = WL + WS_OFF + r*88;
    for (int i = 0; i < 7;  i++) row[i]   = f2bf(wihs[r*7 + i]);
    row[7] = f2bf(bihs[r] + bhhs[r]);
    for (int j = 0; j < 64; j++) row[8+j] = f2bf(whhs[r*64 + j]);
    for (int j = 72; j < 88; j++) row[j] = 0;
  }
  for (int m = tid; m < 384; m += 256) {
    int cell = m >> 7, r = m & 127;
    u16* row = WL + WC_OFF + m*120;
    const float *wih, *whh, *bi, *bh; int L, xoffc;
    if (cell == 0)      { wih=wiha; whh=whha; bi=biha; bh=bhha; L=71; xoffc=64; }
    else if (cell == 1) { wih=wihv; whh=whhv; bi=bihv; bh=bhhv; L=74; xoffc=67; }
    else                { wih=wihp; whh=whhp; bi=bihp; bh=bhhp; L=67; xoffc=-1; }
    for (int i = 0; i < 7; i++)
      row[i] = (xoffc >= 0) ? f2bf(wih[r*L + xoffc + i]) : (u16)0;
    row[7] = f2bf(bi[r] + bh[r]);
    for (int j = 0; j < 32; j++) row[8+j]  = f2bf(whh[r*32 + j]);
    for (int j = 0; j < 64; j++) row[40+j] = f2bf(wih[r*L + j]);
    for (int k = 0; k < 3; k++)
      row[104+k] = (cell >= 1) ? f2bf(wih[r*L + 64 + k]) : (u16)0;
    for (int j = 107; j < 120; j++) row[j] = 0;
  }
  if (tid < 48) {
    int cell = tid >> 4, i = tid & 15;
    const float* w1 = cell==0 ? wa1 : (cell==1 ? wv1 : wp1);
    const float* b1 = cell==0 ? ba1 : (cell==1 ? bv1 : bp1);
    u16* row = WL + WM1_OFF + tid*40;
    for (int j = 0; j < 32; j++) row[j] = f2bf(w1[i*32 + j]);
    row[32] = f2bf(b1[i]);
    for (int j = 33; j < 40; j++) row[j] = 0;
  }
  if (tid < 9) {
    int cell = tid / 3, i = tid % 3;
    const float* w2 = cell==0 ? wa2 : (cell==1 ? wv2 : wp2);
    const float* b2 = cell==0 ? ba2 : (cell==1 ? bv2 : bp2);
    u16* row = WL + WM2_OFF + tid*24;
    for (int j = 0; j < 16; j++) row[j] = f2bf(w2[i*16 + j]);
    row[16] = f2bf(b2[i]);
    for (int j = 17; j < 24; j++) row[j] = 0;
  }
  for (int i = tid; i < FTOT; i += 256) F[i] = 0.f;
  __syncthreads();
  if (tid == 7 || tid == 15) F[XBo + tid] = 1.0f;   // bias slots of both x buffers
  if (tid < 7) F[XBo + tid] = xb[tid];              // x(0) into buffer 0
  __syncthreads();

  // ================= recurrence =================
  float c_s = 0.f, vhs = 0.f;             // per-wave redundant shared state (lane j <-> hidden j)
  float c_a = 0.f, c_v = 0.f, c_p = 0.f;  // wave0 lanes<32 own cell states
  float aacc = 0.f, pacc = 0.f;           // PH-A -> PH-C register handoff (W0/W1)

  #pragma unroll 1
  for (int t = 0; t < NS; t++) {
    const float vx = F[XBo + (t & 1)*8 + (lane & 7)];

    // ---- PH-A: shared z (W2/W3), cell partials hh+x+bias (W0/W1); uses hs(t-1), h*(t-1)
    if (wave < 2) {
      const int r0 = wave*64 + lane;                  // 0..127
      const float vha = F[HAo + (lane & 31)];
      const float vhv = F[HVo + (lane & 31)];
      const float vhp = F[HPo + (lane & 31)];
      const u16* ar = WL + WC_OFF + r0*120;
      const u16* vr = WL + WC_OFF + (128 + r0)*120;
      const u16* pr = WL + WC_OFF + (256 + r0)*120;
      aacc = 0.f; pacc = 0.f; float vacc = 0.f;
      d8<0>(aacc, ld4(ar), vx);                       // x-w + bias (slot7 act = 1.0)
      d8<0>(vacc, ld4(vr), vx);
      d8<0>(pacc, ld4(pr), vx);                       // pos x-w are 0 -> bias only
      dotc4(aacc, ar + 8, vha);                       // hh parts
      dotc4(vacc, vr + 8, vhv);
      dotc4(pacc, pr + 8, vhp);
      F[ZCo + 128 + r0] = vacc;                       // hand vel partial to W2/W3
    } else {
      const int r1 = (wave - 2)*64 + lane;            // 0..127
      const int r2 = r1 + 128;                        // 128..255
      const u16* s1 = WL + WS_OFF + r1*88;
      const u16* s2 = WL + WS_OFF + r2*88;
      float a1 = 0.f, a2 = 0.f;
      d8_2<0>(a1, a2, ld4(s1), ld4(s2), vx);          // x + bias
      dotc8_2(a1, a2, s1 + 8, s2 + 8, vhs);           // hs(t-1)
      F[ZSo + r1] = a1; F[ZSo + r2] = a2;
    }
    __syncthreads();

    // ---- PH-B: hs update, computed redundantly by every wave (registers only)
    {
      float zi = F[ZSo + lane],       zf = F[ZSo + 64 + lane];
      float zg = F[ZSo + 128 + lane], zo = F[ZSo + 192 + lane];
      c_s = sigf(zf)*c_s + sigf(zi)*tanhf_(zg);
      vhs = sigf(zo)*tanhf_(c_s);                     // hs(t), lane j holds hidden j
    }

    // ---- PH-C: hs-dots for att/vel/pos (uses hs(t))
    if (wave < 2) {
      const int r0 = wave*64 + lane;
      const u16* ar = WL + WC_OFF + r0*120;
      const u16* pr = WL + WC_OFF + (256 + r0)*120;
      dotc8(aacc, ar + 40, vhs);                      // att full
      dotc4(pacc, pr + 40, vhs);                      // pos lo half (j 0..31)
      F[ZCo + r0] = aacc;
      F[ZCo + 256 + r0] = pacc;
    } else {
      const int r0 = (wave - 2)*64 + lane;
      const u16* vr = WL + WC_OFF + (128 + r0)*120;
      const u16* pr = WL + WC_OFF + (256 + r0)*120;
      float vacc = F[ZCo + 128 + r0];                 // partial from PH-A (barrier passed)
      dotc8(vacc, vr + 40, vhs);                      // vel full
      float ph = 0.f;
      dotc4hi(ph, pr + 40, vhs);                      // pos hi half (j 32..63)
      F[ZCo + 128 + r0] = vacc;
      F[ZPH + r0] = ph;
    }
    __syncthreads();

    // ---- TAIL: wave0 serial chain; wave1 prefetches x(t+1)
    if (wave == 0) {
      float za0 = F[ZCo + lane],       za1 = F[ZCo + 64 + lane];
      float zv0 = F[ZCo + 128 + lane], zv1 = F[ZCo + 192 + lane];
      float zp0 = F[ZCo + 256 + lane] + F[ZPH + lane];
      float zp1 = F[ZCo + 320 + lane] + F[ZPH + 64 + lane];
      float* ob = out + ((size_t)b * NS + t) * 9;

      // ATT: lane r<32: i=za0, f=swap(za0), g=za1, o=swap(za1)
      float f_ = __shfl_xor(za0, 32), o_ = __shfl_xor(za1, 32);
      c_a = sigf(f_)*c_a + sigf(za0)*tanhf_(za1);
      float han = sigf(o_)*tanhf_(c_a);
      if (lane < 32) F[HAo + lane] = han;
      float q = mlp1f(WL + WM1_OFF + (lane & 15)*40, han);
      float d = mlp2f(WL + WM2_OFF + (lane < 3 ? lane : 0)*24, q);
      if (lane < 3) ob[lane] = d;
      float d0 = rlf<0>(d), d1 = rlf<1>(d), d2 = rlf<2>(d);

      // VEL: add d_att terms, then gate
      {
        const u16* r0w = WL + WC_OFF + (128 + lane)*120;
        const u16* r1w = WL + WC_OFF + (192 + lane)*120;
        zv0 += b16f(r0w[104])*d0 + b16f(r0w[105])*d1 + b16f(r0w[106])*d2;
        zv1 += b16f(r1w[104])*d0 + b16f(r1w[105])*d1 + b16f(r1w[106])*d2;
      }
      f_ = __shfl_xor(zv0, 32); o_ = __shfl_xor(zv1, 32);
      c_v = sigf(f_)*c_v + sigf(zv0)*tanhf_(zv1);
      float hvn = sigf(o_)*tanhf_(c_v);
      if (lane < 32) F[HVo + lane] = hvn;
      q = mlp1f(WL + WM1_OFF + (16 + (lane & 15))*40, hvn);
      d = mlp2f(WL + WM2_OFF + (3 + (lane < 3 ? lane : 0))*24, q);
      if (lane < 3) ob[3 + lane] = d;
      d0 = rlf<0>(d); d1 = rlf<1>(d); d2 = rlf<2>(d);

      // POS: add d_vel terms, then gate
      {
        const u16* r0w = WL + WC_OFF + (256 + lane)*120;
        const u16* r1w = WL + WC_OFF + (320 + lane)*120;
        zp0 += b16f(r0w[104])*d0 + b16f(r0w[105])*d1 + b16f(r0w[106])*d2;
        zp1 += b16f(r1w[104])*d0 + b16f(r1w[105])*d1 + b16f(r1w[106])*d2;
      }
      f_ = __shfl_xor(zp0, 32); o_ = __shfl_xor(zp1, 32);
      c_p = sigf(f_)*c_p + sigf(zp0)*tanhf_(zp1);
      float hpn = sigf(o_)*tanhf_(c_p);
      if (lane < 32) F[HPo + lane] = hpn;
      q = mlp1f(WL + WM1_OFF + (32 + (lane & 15))*40, hpn);
      d = mlp2f(WL + WM2_OFF + (6 + (lane < 3 ? lane : 0))*24, q);
      if (lane < 3) ob[6 + lane] = d;
    } else if (wave == 1) {
      if (lane < 7 && t + 1 < NS)
        F[XBo + ((t + 1) & 1)*8 + lane] = xb[(size_t)(t + 1)*NIN + lane];
    }
    __syncthreads();
  }
}

extern "C" void kernel_launch(void* const* d_in, const int* in_sizes, int n_in,
                              void* d_out, int out_size, void* d_ws, size_t ws_size,
                              hipStream_t stream) {
  (void)in_sizes; (void)n_in; (void)d_ws; (void)ws_size; (void)out_size;
  const float* X    = (const float*)d_in[0];
  const float* Wihs = (const float*)d_in[1];
  const float* Whhs = (const float*)d_in[2];
  const float* Bihs = (const float*)d_in[3];
  const float* Bhhs = (const float*)d_in[4];
  const float* Wiha = (const float*)d_in[5];
  const float* Whha = (const float*)d_in[6];
  const float* Biha = (const float*)d_in[7];
  const float* Bhha = (const float*)d_in[8];
  const float* Wihv = (const float*)d_in[9];
  const float* Whhv = (const float*)d_in[10];
  const float* Bihv = (const float*)d_in[11];
  const float* Bhhv = (const float*)d_in[12];
  const float* Wihp = (const float*)d_in[13];
  const float* Whhp = (const float*)d_in[14];
  const float* Bihp = (const float*)d_in[15];
  const float* Bhhp = (const float*)d_in[16];
  const float* Wa1  = (const float*)d_in[17];
  const float* Ba1  = (const float*)d_in[18];
  const float* Wa2  = (const float*)d_in[19];
  const float* Ba2  = (const float*)d_in[20];
  const float* Wv1  = (const float*)d_in[21];
  const float* Bv1  = (const float*)d_in[22];
  const float* Wv2  = (const float*)d_in[23];
  const float* Bv2  = (const float*)d_in[24];
  const float* Wp1  = (const float*)d_in[25];
  const float* Bp1  = (const float*)d_in[26];
  const float* Wp2  = (const float*)d_in[27];
  const float* Bp2  = (const float*)d_in[28];
  float* OUTP = (float*)d_out;

  hipFuncSetAttribute(reinterpret_cast<const void*>(mtinn_kernel),
                      hipFuncAttributeMaxDynamicSharedMemorySize, (int)SMEM_BYTES);

  mtinn_kernel<<<dim3(NB), dim3(256), SMEM_BYTES, stream>>>(
      X, Wihs, Whhs, Bihs, Bhhs,
      Wiha, Whha, Biha, Bhha,
      Wihv, Whhv, Bihv, Bhhv,
      Wihp, Whhp, Bihp, Bhhp,
      Wa1, Ba1, Wa2, Ba2, Wv1, Bv1, Wv2, Bv2, Wp1, Bp1, Wp2, Bp2,
      OUTP);
}

// Round 5
// 6372.703 us; speedup vs baseline: 1.2883x; 1.2883x over previous
//
#include <hip/hip_runtime.h>

#define NIN 7
#define NB 256
#define NS 2048

__device__ __forceinline__ float fastrcp(float x){ return __builtin_amdgcn_rcpf(x); }
__device__ __forceinline__ float sigf(float x){ return fastrcp(1.f + __expf(-x)); }
__device__ __forceinline__ float tanhf_(float x){ return 1.f - 2.f*fastrcp(1.f + __expf(2.f*x)); }

template<int J>
__device__ __forceinline__ float rlf(float v){
  return __uint_as_float((unsigned)__builtin_amdgcn_readlane((int)__float_as_uint(v), J));
}

// zM = rows lo-half (i|f), zL = rows hi-half (g|o); update c, return h[lane&31]
__device__ __forceinline__ float cellgate(float zM, float zL, float& c, int lane){
  float zMs = __shfl_xor(zM, 32), zLs = __shfl_xor(zL, 32);
  bool lo = lane < 32;
  float zi = lo ? zM  : zMs;
  float zf = lo ? zMs : zM;
  float zg = lo ? zL  : zLs;
  float zo = lo ? zLs : zL;
  c = sigf(zf)*c + sigf(zi)*tanhf_(zg);
  return sigf(zo)*tanhf_(c);
}

// acc += wreg[B..B+3] dot v   (B must be a compile-time constant expression)
#define FMA4(acc, B, v) { acc += wreg[(B)+0]*(v).x; acc += wreg[(B)+1]*(v).y; \
                          acc += wreg[(B)+2]*(v).z; acc += wreg[(B)+3]*(v).w; }
#define DOT4(acc, m, v) { acc += (m).x*(v).x; acc += (m).y*(v).y; \
                          acc += (m).z*(v).z; acc += (m).w*(v).w; }

__global__ __launch_bounds__(256, 1) void mtinn_kernel(
    const float* __restrict__ x,
    const float* wihs, const float* whhs, const float* bihs, const float* bhhs,
    const float* wiha, const float* whha, const float* biha, const float* bhha,
    const float* wihv, const float* whhv, const float* bihv, const float* bhhv,
    const float* wihp, const float* whhp, const float* bihp, const float* bhhp,
    const float* wa1, const float* ba1, const float* wa2, const float* ba2,
    const float* wv1, const float* bv1, const float* wv2, const float* bv2,
    const float* wp1, const float* bp1, const float* wp2, const float* bp2,
    float* __restrict__ out)
{
  __shared__ __align__(16) float ZS[2][256];   // shared-cell z, double buffered
  __shared__ __align__(16) float ZV[128];      // vel z all rows
  __shared__ __align__(16) float ZA1[64];      // att rows 64..127 (g|o)
  __shared__ __align__(16) float ZP1[64];      // pos rows 64..127 (g|o)
  __shared__ __align__(16) float HSs[4][64];   // per-wave hs copies
  __shared__ __align__(16) float HA[32], HV[32], HP[32];
  __shared__ __align__(16) float XL[4][8];     // x ring buffer
  __shared__ __align__(16) float QT[16];
  __shared__ __align__(16) float M1[3][16][36];  // [0..31]=W1 row, [32]=b1
  __shared__ __align__(16) float M2[3][3][20];   // [0..15]=W2 row, [16]=b2

  const int tid  = threadIdx.x;
  const int wave = tid >> 6, lane = tid & 63;
  const int b    = blockIdx.x;
  const float* xb = x + (size_t)b * NS * NIN;
  const int mi = lane & 15, mm = lane % 3;

  // ---- overlaid f32 register weights ----
  // waves 0/1 (att row r, pos row r; r = wave*64+lane):
  //   [0..31] att hh | [32..95] att hs | [96..102] att x | [103] att b
  //   [104..135] pos hh | [136..199] pos hs | [200] pos b
  //   wave0 only: [201..203] velD row lane | [204..206] velD row 64+lane
  //               [207..209] posD row lane | [210..212] posD row 64+lane
  // waves 2/3 (shared rows rA, rA+128; vel row rA; rA = (wave&1)*64+lane):
  //   [0..63] shA hs | [64..70] shA x | [71] shA b
  //   [72..135] shB hs | [136..142] shB x | [143] shB b
  //   [144..175] vel hh | [176..239] vel hs | [240..246] vel x | [247] vel b
  float wreg[248];
#pragma unroll
  for (int i = 0; i < 248; i++) wreg[i] = 0.f;

  if (wave < 2){
    const int r = wave*64 + lane;
#pragma unroll
    for (int k=0;k<32;k++) wreg[k]     = whha[r*32+k];
#pragma unroll
    for (int k=0;k<64;k++) wreg[32+k]  = wiha[r*71+k];
#pragma unroll
    for (int k=0;k<7;k++)  wreg[96+k]  = wiha[r*71+64+k];
    wreg[103] = biha[r] + bhha[r];
#pragma unroll
    for (int k=0;k<32;k++) wreg[104+k] = whhp[r*32+k];
#pragma unroll
    for (int k=0;k<64;k++) wreg[136+k] = wihp[r*67+k];
    wreg[200] = bihp[r] + bhhp[r];
    if (wave == 0){
#pragma unroll
      for (int k=0;k<3;k++){
        wreg[201+k] = wihv[lane*74+64+k];
        wreg[204+k] = wihv[(64+lane)*74+64+k];
        wreg[207+k] = wihp[lane*67+64+k];
        wreg[210+k] = wihp[(64+lane)*67+64+k];
      }
    }
  } else {
    const int rA = (wave&1)*64 + lane;
    const int rB = rA + 128;
#pragma unroll
    for (int k=0;k<64;k++) wreg[k]      = whhs[rA*64+k];
#pragma unroll
    for (int k=0;k<7;k++)  wreg[64+k]   = wihs[rA*7+k];
    wreg[71] = bihs[rA] + bhhs[rA];
#pragma unroll
    for (int k=0;k<64;k++) wreg[72+k]   = whhs[rB*64+k];
#pragma unroll
    for (int k=0;k<7;k++)  wreg[136+k]  = wihs[rB*7+k];
    wreg[143] = bihs[rB] + bhhs[rB];
#pragma unroll
    for (int k=0;k<32;k++) wreg[144+k]  = whhv[rA*32+k];
#pragma unroll
    for (int k=0;k<64;k++) wreg[176+k]  = wihv[rA*74+k];
#pragma unroll
    for (int k=0;k<7;k++)  wreg[240+k]  = wihv[rA*74+67+k];
    wreg[247] = bihv[rA] + bhhv[rA];
  }

  // ---- LDS init ----
  if (tid < 48){
    int task = tid>>4, row = tid&15;
    const float* w1 = task==0?wa1:(task==1?wv1:wp1);
    const float* b1 = task==0?ba1:(task==1?bv1:bp1);
    for (int j=0;j<32;j++) M1[task][row][j] = w1[row*32+j];
    M1[task][row][32] = b1[row];
    M1[task][row][33] = M1[task][row][34] = M1[task][row][35] = 0.f;
  }
  if (tid < 9){
    int task = tid/3, row = tid%3;
    const float* w2 = task==0?wa2:(task==1?wv2:wp2);
    const float* b2 = task==0?ba2:(task==1?bv2:bp2);
    for (int j=0;j<16;j++) M2[task][row][j] = w2[row*16+j];
    M2[task][row][16] = b2[row];
    M2[task][row][17] = M2[task][row][18] = M2[task][row][19] = 0.f;
  }
  if (tid < 32){ HA[tid]=0.f; HV[tid]=0.f; HP[tid]=0.f; }
  if (tid < 8){ XL[0][tid] = (tid<7)?xb[tid]:0.f; XL[1][tid] = (tid<7)?xb[NIN+tid]:0.f;
                XL[2][tid]=0.f; XL[3][tid]=0.f; }
  __syncthreads();

  // zS(0) = b + Wih x(0)
  if (wave >= 2){
    const float4* Xc = (const float4*)XL[0];
    float4 x0 = Xc[0], x1 = Xc[1];
    float sA = wreg[71];  FMA4(sA, 64, x0);
    sA += wreg[68]*x1.x + wreg[69]*x1.y + wreg[70]*x1.z;
    float sB = wreg[143]; FMA4(sB, 136, x0);
    sB += wreg[140]*x1.x + wreg[141]*x1.y + wreg[142]*x1.z;
    const int rA = (wave&1)*64 + lane;
    ZS[0][rA] = sA; ZS[0][rA+128] = sB;
  }
  __syncthreads();
  float zni = ZS[0][lane], znf = ZS[0][64+lane], zng = ZS[0][128+lane], zno = ZS[0][192+lane];
  float c_s = 0.f, c_a = 0.f, c_v = 0.f, c_p = 0.f;

  // ================= recurrence =================
#pragma unroll 1
  for (int t = 0; t < NS; t++){
    // global prefetch x(t+2) (wave 1, consumed after barrier #1)
    float xpre = 0.f;
    if (wave == 1 && lane < 7){
      const int tf = (t+2 < NS) ? t+2 : NS-1;
      xpre = xb[(size_t)tf*NIN + lane];
    }

    // ---- PH-1: shared gates (registers) ----
    c_s = sigf(znf)*c_s + sigf(zni)*tanhf_(zng);
    const float hsv = sigf(zno)*tanhf_(c_s);
    HSs[wave][lane] = hsv;
    const float4* Hw = (const float4*)HSs[wave];

    // ---- PH-2: dot products ----
    float* ZSn = ZS[(t+1)&1];
    float zAr = 0.f, zPr = 0.f;                    // wave 0 keeps its rows in regs
    if (wave < 2){
      const float4* Ha4 = (const float4*)HA;
      const float4* Hp4 = (const float4*)HP;
      const float4* Xc  = (const float4*)XL[t&3];
      float a0 = wreg[103], a1 = 0.f, p0 = wreg[200], p1 = 0.f;
#pragma unroll
      for (int c=0;c<8;c++){
        float4 ha_ = Ha4[c], hp_ = Hp4[c];
        if (c&1){ FMA4(a1, 4*c,       ha_); FMA4(p1, 104+4*c, hp_); }
        else    { FMA4(a0, 4*c,       ha_); FMA4(p0, 104+4*c, hp_); }
      }
#pragma unroll
      for (int c=0;c<16;c++){
        float4 h = Hw[c];
        if (c&1){ FMA4(a1, 32+4*c, h); FMA4(p1, 136+4*c, h); }
        else    { FMA4(a0, 32+4*c, h); FMA4(p0, 136+4*c, h); }
      }
      float4 x0 = Xc[0], x1 = Xc[1];
      FMA4(a0, 96, x0);
      a1 += wreg[100]*x1.x + wreg[101]*x1.y + wreg[102]*x1.z;
      const float zA = a0+a1, zP = p0+p1;
      if (wave == 1){ ZA1[lane] = zA; ZP1[lane] = zP; }
      else { zAr = zA; zPr = zP; }
    } else {
      const float4* Hv4 = (const float4*)HV;
      const float4* Xc  = (const float4*)XL[t&3];       // x(t) for vel
      const float4* Xn  = (const float4*)XL[(t+1)&3];   // x(t+1) for shared
      float sA0 = wreg[71], sA1 = 0.f, sB0 = wreg[143], sB1 = 0.f;
      float v0 = wreg[247], v1 = 0.f;
#pragma unroll
      for (int c=0;c<16;c++){
        float4 h = Hw[c];
        if (c&1){ FMA4(sA1, 4*c, h); FMA4(sB1, 72+4*c, h); FMA4(v1, 176+4*c, h); }
        else    { FMA4(sA0, 4*c, h); FMA4(sB0, 72+4*c, h); FMA4(v0, 176+4*c, h); }
      }
#pragma unroll
      for (int c=0;c<8;c++){
        float4 hv_ = Hv4[c];
        if (c&1){ FMA4(v1, 144+4*c, hv_); } else { FMA4(v0, 144+4*c, hv_); }
      }
      float4 xn0 = Xn[0], xn1 = Xn[1];
      FMA4(sA0, 64, xn0);
      sA1 += wreg[68]*xn1.x + wreg[69]*xn1.y + wreg[70]*xn1.z;
      FMA4(sB0, 136, xn0);
      sB1 += wreg[140]*xn1.x + wreg[141]*xn1.y + wreg[142]*xn1.z;
      float4 x0 = Xc[0], x1 = Xc[1];
      FMA4(v0, 240, x0);
      v1 += wreg[244]*x1.x + wreg[245]*x1.y + wreg[246]*x1.z;
      const int rA = (wave&1)*64 + lane;
      ZSn[rA] = sA0+sA1; ZSn[rA+128] = sB0+sB1; ZV[rA] = v0+v1;
    }
    __syncthreads();   // #1

    // prefetch next-step shared z (latency hidden under tail)
    zni = ZSn[lane]; znf = ZSn[64+lane]; zng = ZSn[128+lane]; zno = ZSn[192+lane];

    // ---- TAIL: wave 0 serial chain ----
    if (wave == 0){
      float* ob = out + ((size_t)b*NS + t)*9;
      const float4* QT4 = (const float4*)QT;
      const float4* HA4 = (const float4*)HA;
      const float4* HV4 = (const float4*)HV;
      const float4* HP4 = (const float4*)HP;

      // ===== ATT =====
      const float4* MA = (const float4*)M1[0][mi];
      const float4* MB = (const float4*)M2[0][mm];
      float4 ma0=MA[0],ma1=MA[1],ma2=MA[2],ma3=MA[3],ma4=MA[4],ma5=MA[5],ma6=MA[6],ma7=MA[7];
      float b1A = M1[0][mi][32];
      float4 mb0=MB[0],mb1=MB[1],mb2=MB[2],mb3=MB[3];
      float b2A = M2[0][mm][16];
      float zHa = ZA1[lane];
      float hA_ = cellgate(zAr, zHa, c_a, lane);
      if (lane < 32) HA[lane] = hA_;
      float4 h0=HA4[0],h1=HA4[1],h2=HA4[2],h3=HA4[3],h4=HA4[4],h5=HA4[5],h6=HA4[6],h7=HA4[7];
      float q0=b1A, q1=0.f;
      DOT4(q0,ma0,h0); DOT4(q1,ma1,h1); DOT4(q0,ma2,h2); DOT4(q1,ma3,h3);
      DOT4(q0,ma4,h4); DOT4(q1,ma5,h5); DOT4(q0,ma6,h6); DOT4(q1,ma7,h7);
      float qv = fmaxf(q0+q1, 0.f);
      if (lane < 16) QT[lane] = qv;
      float4 qq0=QT4[0],qq1=QT4[1],qq2=QT4[2],qq3=QT4[3];
      float e0=b2A, e1=0.f;
      DOT4(e0,mb0,qq0); DOT4(e1,mb1,qq1); DOT4(e0,mb2,qq2); DOT4(e1,mb3,qq3);
      float dA = e0+e1;
      if (lane < 3) ob[lane] = dA;
      float dx = rlf<0>(dA), dy = rlf<1>(dA), dz = rlf<2>(dA);

      // ===== VEL =====
      const float4* MAv = (const float4*)M1[1][mi];
      const float4* MBv = (const float4*)M2[1][mm];
      float4 va0=MAv[0],va1=MAv[1],va2=MAv[2],va3=MAv[3],va4=MAv[4],va5=MAv[5],va6=MAv[6],va7=MAv[7];
      float b1V = M1[1][mi][32];
      float4 vb0=MBv[0],vb1=MBv[1],vb2=MBv[2],vb3=MBv[3];
      float b2V = M2[1][mm][16];
      float zVlo = ZV[lane]      + wreg[201]*dx + wreg[202]*dy + wreg[203]*dz;
      float zVhi = ZV[64+lane]   + wreg[204]*dx + wreg[205]*dy + wreg[206]*dz;
      float hV_ = cellgate(zVlo, zVhi, c_v, lane);
      if (lane < 32) HV[lane] = hV_;
      float4 g0=HV4[0],g1=HV4[1],g2=HV4[2],g3=HV4[3],g4=HV4[4],g5=HV4[5],g6=HV4[6],g7=HV4[7];
      q0=b1V; q1=0.f;
      DOT4(q0,va0,g0); DOT4(q1,va1,g1); DOT4(q0,va2,g2); DOT4(q1,va3,g3);
      DOT4(q0,va4,g4); DOT4(q1,va5,g5); DOT4(q0,va6,g6); DOT4(q1,va7,g7);
      qv = fmaxf(q0+q1, 0.f);
      if (lane < 16) QT[lane] = qv;
      qq0=QT4[0]; qq1=QT4[1]; qq2=QT4[2]; qq3=QT4[3];
      e0=b2V; e1=0.f;
      DOT4(e0,vb0,qq0); DOT4(e1,vb1,qq1); DOT4(e0,vb2,qq2); DOT4(e1,vb3,qq3);
      float dV = e0+e1;
      if (lane < 3) ob[3+lane] = dV;
      dx = rlf<0>(dV); dy = rlf<1>(dV); dz = rlf<2>(dV);

      // ===== POS =====
      const float4* MAp = (const float4*)M1[2][mi];
      const float4* MBp = (const float4*)M2[2][mm];
      float4 pa0=MAp[0],pa1=MAp[1],pa2=MAp[2],pa3=MAp[3],pa4=MAp[4],pa5=MAp[5],pa6=MAp[6],pa7=MAp[7];
      float b1P = M1[2][mi][32];
      float4 pb0=MBp[0],pb1=MBp[1],pb2=MBp[2],pb3=MBp[3];
      float b2P = M2[2][mm][16];
      float zPlo = zPr        + wreg[207]*dx + wreg[208]*dy + wreg[209]*dz;
      float zPhi = ZP1[lane]  + wreg[210]*dx + wreg[211]*dy + wreg[212]*dz;
      float hP_ = cellgate(zPlo, zPhi, c_p, lane);
      if (lane < 32) HP[lane] = hP_;
      float4 r0=HP4[0],r1=HP4[1],r2=HP4[2],r3=HP4[3],r4=HP4[4],r5=HP4[5],r6=HP4[6],r7=HP4[7];
      q0=b1P; q1=0.f;
      DOT4(q0,pa0,r0); DOT4(q1,pa1,r1); DOT4(q0,pa2,r2); DOT4(q1,pa3,r3);
      DOT4(q0,pa4,r4); DOT4(q1,pa5,r5); DOT4(q0,pa6,r6); DOT4(q1,pa7,r7);
      qv = fmaxf(q0+q1, 0.f);
      if (lane < 16) QT[lane] = qv;
      qq0=QT4[0]; qq1=QT4[1]; qq2=QT4[2]; qq3=QT4[3];
      e0=b2P; e1=0.f;
      DOT4(e0,pb0,qq0); DOT4(e1,pb1,qq1); DOT4(e0,pb2,qq2); DOT4(e1,pb3,qq3);
      float dP = e0+e1;
      if (lane < 3) ob[6+lane] = dP;
    } else if (wave == 1){
      if (lane < 7) XL[(t+2)&3][lane] = xpre;
    }
    __syncthreads();   // #2
  }
}

extern "C" void kernel_launch(void* const* d_in, const int* in_sizes, int n_in,
                              void* d_out, int out_size, void* d_ws, size_t ws_size,
                              hipStream_t stream) {
  (void)in_sizes; (void)n_in; (void)d_ws; (void)ws_size; (void)out_size;
  const float* X    = (const float*)d_in[0];
  const float* Wihs = (const float*)d_in[1];
  const float* Whhs = (const float*)d_in[2];
  const float* Bihs = (const float*)d_in[3];
  const float* Bhhs = (const float*)d_in[4];
  const float* Wiha = (const float*)d_in[5];
  const float* Whha = (const float*)d_in[6];
  const float* Biha = (const float*)d_in[7];
  const float* Bhha = (const float*)d_in[8];
  const float* Wihv = (const float*)d_in[9];
  const float* Whhv = (const float*)d_in[10];
  const float* Bihv = (const float*)d_in[11];
  const float* Bhhv = (const float*)d_in[12];
  const float* Wihp = (const float*)d_in[13];
  const float* Whhp = (const float*)d_in[14];
  const float* Bihp = (const float*)d_in[15];
  const float* Bhhp = (const float*)d_in[16];
  const float* Wa1  = (const float*)d_in[17];
  const float* Ba1  = (const float*)d_in[18];
  const float* Wa2  = (const float*)d_in[19];
  const float* Ba2  = (const float*)d_in[20];
  const float* Wv1  = (const float*)d_in[21];
  const float* Bv1  = (const float*)d_in[22];
  const float* Wv2  = (const float*)d_in[23];
  const float* Bv2  = (const float*)d_in[24];
  const float* Wp1  = (const float*)d_in[25];
  const float* Bp1  = (const float*)d_in[26];
  const float* Wp2  = (const float*)d_in[27];
  const float* Bp2  = (const float*)d_in[28];
  float* OUTP = (float*)d_out;

  mtinn_kernel<<<dim3(NB), dim3(256), 0, stream>>>(
      X, Wihs, Whhs, Bihs, Bhhs,
      Wiha, Whha, Biha, Bhha,
      Wihv, Whhv, Bihv, Bhhv,
      Wihp, Whhp, Bihp, Bhhp,
      Wa1, Ba1, Wa2, Ba2, Wv1, Bv1, Wv2, Bv2, Wp1, Bp1, Wp2, Bp2,
      OUTP);
}